// Round 1
// 174.440 us; speedup vs baseline: 1.1258x; 1.1258x over previous
//
#include <hip/hip_runtime.h>

// obj = (99*sum_t ||c_t||^2 + ||sum_t c_t||^2)/100 (Parseval over the 100
// samples = 99th roots of unity, z=1 double-counted), c_0 = D_F,
// c_{k+1} = E_k = C_F A_F^k B_F - C A^k B, B = eye(256,128).
// DOUBLE-STEP with bf16 constant matrices:
//   pre1: split-K partials of A2=AF^2, W1=AF*BF, AH2=A^2 (fp32 acc, bf16 B)
//   pre2: resolve partials; convert A2,W1,AH2,BF,A to packed bf16 (r|i<<16)
//   dstep s: Ee_s = QF*BFb - QH[:,:128]; Eo_s = QF*W1b - QH*Ab[:,:128];
//            QF <- QF*A2b; QH <- QH*AH2b   (Q fp32, B-slabs bf16)
// This revision: PERSISTENT LDS B-slab (whole KD x 128 staged once, single
// __syncthreads, barrier-free flat K loop) in pre1 + dstep — removes the
// 8-12 per-chunk block barriers that left the 2-blocks/CU pipeline
// latency-bound; out_kernel merged into finalize via ticket (7 dispatches).
// Numerics: dstep accumulation order unchanged (bit-identical); pre1 now
// rounds its B operand to bf16 (outputs were bf16-bound anyway).

#define KSTEPS 4   // double-steps -> E_0..E_7

struct Params {
    const float *AFr, *AFi, *Ar, *Ai, *BFr, *BFi, *CFr, *CFi, *Cr, *Ci, *DFr, *DFi;
    float2 *A2p, *W1p, *AH2p;                 // pre1 split-K partials (x4)
    unsigned int *A2b, *W1b, *AH2b, *BFb, *Ab;  // packed bf16 constants
    float2 *QFp0, *QFp1, *QHp0, *QHp1, *Eep0, *Eep1, *Eop0, *Eop1, *Sm;
    float *S1, *S2, *SD, *out;
    unsigned int *tick;
};

__device__ __forceinline__ unsigned int f2bf2(float r, float i) {
    unsigned int ur = __float_as_uint(r); ur = (ur + 0x7fffu + ((ur >> 16) & 1u)) >> 16;
    unsigned int ui = __float_as_uint(i); ui = (ui + 0x7fffu + ((ui >> 16) & 1u)) >> 16;
    return ur | (ui << 16);
}

__device__ __forceinline__ float block_reduce(float v, float* red, int tid) {
    red[tid] = v;
    __syncthreads();
    for (int off = 128; off > 0; off >>= 1) {
        if (tid < off) red[tid] += red[tid + off];
        __syncthreads();
    }
    float r = red[0];
    __syncthreads();
    return r;
}

// Barrier-free complex inner product: Q (fp32, LDS broadcast rows) x
// B (bf16-packed, LDS persistent slab), 2x2 output tile per thread.
template<int KD>
__device__ __forceinline__ void cmul_inner(const unsigned int* __restrict__ sBu,
                                           const float2 (*__restrict__ sQ)[8],
                                           int w, int lane, float acc[8]) {
    #pragma unroll 8
    for (int kk = 0; kk < KD; ++kk) {
        float4 qv = *(const float4*)&sQ[kk][2 * w];
        uint2 bu = *(const uint2*)&sBu[(kk << 7) + 2 * lane];
        float b0r = __uint_as_float(bu.x << 16);
        float b0i = __uint_as_float(bu.x & 0xffff0000u);
        float b1r = __uint_as_float(bu.y << 16);
        float b1i = __uint_as_float(bu.y & 0xffff0000u);
        acc[0] += qv.x * b0r - qv.y * b0i;  acc[1] += qv.x * b0i + qv.y * b0r;
        acc[2] += qv.x * b1r - qv.y * b1i;  acc[3] += qv.x * b1i + qv.y * b1r;
        acc[4] += qv.z * b0r - qv.w * b0i;  acc[5] += qv.z * b0i + qv.w * b0r;
        acc[6] += qv.z * b1r - qv.w * b1i;  acc[7] += qv.z * b1i + qv.w * b1r;
    }
}

// ---------------- pre1: split-K partials of A2, W1, AH2 (1024 blocks) --------
//  [0,576):    A2 = AF*AF: 144 tiles (48 rg x 3 cs) x 4 parts (KD 96)
//  [576,768):  W1 = AF*BF: 48 rg x 4 parts (KD 96)
//  [768,1024): AH2 = A*A:  64 tiles (32 rg x 2 cs) x 4 parts (KD 64)
template<int KD>
__device__ __forceinline__ void pre1_body(const float* __restrict__ Qr_,
        const float* __restrict__ Qi_, const float* __restrict__ Br_,
        const float* __restrict__ Bi_, int Wq, int Wb, int rg, int c0, int k0,
        unsigned int* sBu, float2 (*sQ)[8], int w, int lane, float acc[8]) {
    const int tid = threadIdx.x;
    // stage whole B slab, converting fp32 pairs -> packed bf16 on the fly
    for (int slot = tid; slot < KD * 32; slot += 256) {
        int row = slot >> 5, cq = (slot & 31) << 2;
        int g = (k0 + row) * Wb + c0 + cq;
        float4 vr = *(const float4*)&Br_[g];
        float4 vi = *(const float4*)&Bi_[g];
        *(uint4*)&sBu[(row << 7) + cq] = make_uint4(
            f2bf2(vr.x, vi.x), f2bf2(vr.y, vi.y), f2bf2(vr.z, vi.z), f2bf2(vr.w, vi.w));
    }
    // stage Q rows rg*8..+7 over [k0,k0+KD)
    for (int slot = tid; slot < 8 * KD; slot += 256) {
        int row = slot / KD, kk = slot - row * KD;
        int g = (rg * 8 + row) * Wq + k0 + kk;
        sQ[kk][row] = make_float2(Qr_[g], Qi_[g]);
    }
    __syncthreads();
    cmul_inner<KD>(sBu, sQ, w, lane, acc);
}

__global__ __launch_bounds__(256, 2)
void pre1_kernel(Params P) {
    __shared__ __align__(16) unsigned int sBu[96 * 128];  // 48 KB
    __shared__ __align__(16) float2 sQ[96][8];            // 6 KB
    const int b = blockIdx.x, tid = threadIdx.x;
    const int w = tid >> 6, lane = tid & 63;
    int rg, c0 = 0, k0, Wq, Wb, Wo, part;
    const float *Qr_, *Qi_, *Br_, *Bi_;
    float2* O;
    bool kd96;
    if (b < 576) {
        int tile = b >> 2; part = b & 3; rg = tile / 3; int cs = tile - 3 * rg;
        c0 = cs << 7; k0 = part * 96; Wq = 384; Wb = 384; Wo = 384;
        Qr_ = P.AFr; Qi_ = P.AFi; Br_ = P.AFr; Bi_ = P.AFi; O = P.A2p + part * 147456;
        kd96 = true;
    } else if (b < 768) {
        int u = b - 576; rg = u >> 2; part = u & 3;
        k0 = part * 96; Wq = 384; Wb = 128; Wo = 128;
        Qr_ = P.AFr; Qi_ = P.AFi; Br_ = P.BFr; Bi_ = P.BFi; O = P.W1p + part * 49152;
        kd96 = true;
    } else {
        int u = b - 768; int tile = u >> 2; part = u & 3; rg = tile >> 1; int cs = tile & 1;
        c0 = cs << 7; k0 = part * 64; Wq = 256; Wb = 256; Wo = 256;
        Qr_ = P.Ar; Qi_ = P.Ai; Br_ = P.Ar; Bi_ = P.Ai; O = P.AH2p + part * 65536;
        kd96 = false;
    }
    float acc[8] = {};
    if (kd96) pre1_body<96>(Qr_, Qi_, Br_, Bi_, Wq, Wb, rg, c0, k0, sBu, sQ, w, lane, acc);
    else      pre1_body<64>(Qr_, Qi_, Br_, Bi_, Wq, Wb, rg, c0, k0, sBu, sQ, w, lane, acc);
    const int prow = rg * 8 + 2 * w, pcol = c0 + 2 * lane;
    *(float4*)&O[prow * Wo + pcol]       = make_float4(acc[0], acc[1], acc[2], acc[3]);
    *(float4*)&O[(prow + 1) * Wo + pcol] = make_float4(acc[4], acc[5], acc[6], acc[7]);
}

// ------------- pre2: resolve pre1 partials -> bf16; convert BF, A -----------
__global__ __launch_bounds__(256)
void pre2_kernel(Params P) {
    int idx = blockIdx.x * 256 + threadIdx.x;
    if (idx < 147456) {
        float2 a = P.A2p[idx], b = P.A2p[147456 + idx];
        float2 c = P.A2p[294912 + idx], d = P.A2p[442368 + idx];
        P.A2b[idx] = f2bf2(a.x + b.x + c.x + d.x, a.y + b.y + c.y + d.y);
    } else if (idx < 196608) {
        int j = idx - 147456;
        float2 a = P.W1p[j], b = P.W1p[49152 + j];
        float2 c = P.W1p[98304 + j], d = P.W1p[147456 + j];
        P.W1b[j] = f2bf2(a.x + b.x + c.x + d.x, a.y + b.y + c.y + d.y);
    } else if (idx < 262144) {
        int j = idx - 196608;
        float2 a = P.AH2p[j], b = P.AH2p[65536 + j];
        float2 c = P.AH2p[131072 + j], d = P.AH2p[196608 + j];
        P.AH2b[j] = f2bf2(a.x + b.x + c.x + d.x, a.y + b.y + c.y + d.y);
    } else if (idx < 311296) {
        int j = idx - 262144;
        P.BFb[j] = f2bf2(P.BFr[j], P.BFi[j]);
    } else if (idx < 376832) {
        int j = idx - 311296;
        P.Ab[j] = f2bf2(P.Ar[j], P.Ai[j]);
    }
}

// ---------------- double-step GEMM: fp32 Q x bf16 B, 2x2 tile ---------------
// Persistent B slab: whole KD x 128 staged to LDS once; single barrier;
// flat barrier-free K loop. Accumulation order identical to prior version.
template<int KD, int QD>
__device__ __forceinline__ void dgemm_bf(
    const unsigned int* __restrict__ Bb, int Wb, int c0, int k0,
    const float* __restrict__ Q0r, const float* __restrict__ Q0i,
    const float2* __restrict__ Qrd, int s, int rg,
    unsigned int* sBu, float2 (*sQ)[8], float acc[8]) {
    const int tid = threadIdx.x;
    const int w = tid >> 6, lane = tid & 63;
    // stage step-invariant bf16 B slab (KD x 128)
    for (int slot = tid; slot < KD * 32; slot += 256) {
        int row = slot >> 5, cq = (slot & 31) << 2;
        *(uint4*)&sBu[(row << 7) + cq] = *(const uint4*)&Bb[(k0 + row) * Wb + c0 + cq];
    }
    // stage Q rows rg*8..+7 over [k0,k0+KD), resolving split-K partials (x4)
    constexpr int qsz = 128 * QD;
    for (int slot = tid; slot < 8 * KD; slot += 256) {
        int row = slot / KD, kk = slot - row * KD;
        int g = (rg * 8 + row) * QD + k0 + kk;
        float2 q;
        if (s == 0) {
            q = make_float2(Q0r[g], Q0i[g]);
        } else {
            float2 v0 = Qrd[g], v1 = Qrd[qsz + g];
            float2 v2 = Qrd[2 * qsz + g], v3 = Qrd[3 * qsz + g];
            q = make_float2(v0.x + v1.x + v2.x + v3.x, v0.y + v1.y + v2.y + v3.y);
        }
        sQ[kk][row] = q;
    }
    __syncthreads();
    cmul_inner<KD>(sBu, sQ, w, lane, acc);
}

// Grid 512 (full) x 256 threads, 8x128 out tile, fan-in 4:
//  [0,192):   F:  QF*A2b. 48 tiles (16 rg x 3 cs) x 4 parts (KD 96)
//  [192,256): Ee: QF*BFb. 16 rg x 4 parts (KD 96); part0 subtracts QH[:,:128];
//             ALL Ee blocks resolve E_{s-1} -> Sm/S1 (init Sm at s=0)
//  [256,320): Eo1: QF*W1b -> Eo parts 0..3
//  [320,384): Eo2: -QH*Ab[:,:128] (KD 64) -> Eo parts 4..7
//  [384,512): H:  QH*AH2b. 32 tiles (16 rg x 2 cs) x 4 parts (KD 64)
__global__ __launch_bounds__(256, 2)
void dstep_kernel(Params P, int s, int base) {
    __shared__ __align__(16) unsigned int sBu[96 * 128];  // 48 KB
    __shared__ __align__(16) float2 sQ[96][8];            // 6 KB
    __shared__ float red[256];
    const int b = blockIdx.x + base, tid = threadIdx.x;
    const int w = tid >> 6, lane = tid & 63;

    const float2* QFrd = (s & 1) ? P.QFp1 : P.QFp0;
    float2*       QFwr = (s & 1) ? P.QFp0 : P.QFp1;
    const float2* QHrd = (s & 1) ? P.QHp1 : P.QHp0;
    float2*       QHwr = (s & 1) ? P.QHp0 : P.QHp1;
    const float2* Eerd = (s & 1) ? P.Eep1 : P.Eep0;
    float2*       Eewr = (s & 1) ? P.Eep0 : P.Eep1;
    const float2* Eord = (s & 1) ? P.Eop1 : P.Eop0;
    float2*       Eowr = (s & 1) ? P.Eop0 : P.Eop1;

    float acc[8] = {};

    if (b < 192) {                       // ---- F: QF*A2b
        int tile = b >> 2, part = b & 3;
        int rg = tile / 3, cs = tile - 3 * rg;
        dgemm_bf<96, 384>(P.A2b, 384, cs << 7, part * 96, P.CFr, P.CFi, QFrd, s, rg, sBu, sQ, acc);
        float2* O = QFwr + part * 49152;
        const int prow = rg * 8 + 2 * w, pcol = (cs << 7) + 2 * lane;
        *(float4*)&O[prow * 384 + pcol]       = make_float4(acc[0], acc[1], acc[2], acc[3]);
        *(float4*)&O[(prow + 1) * 384 + pcol] = make_float4(acc[4], acc[5], acc[6], acc[7]);
    } else if (b < 256) {                // ---- Ee: QF*BFb (+duties)
        int u = b - 192, rg = u >> 2, part = u & 3;
        if (s == 0) {
            int i = u * 256 + tid;
            P.Sm[i] = make_float2(P.DFr[i], P.DFi[i]);
            if (b == 192 && tid == 0) { *P.S1 = 0.f; *P.S2 = 0.f; *P.SD = 0.f; *P.tick = 0u; }
        } else {
            int i = u * 256 + tid;
            float er = 0.f, ei = 0.f;
            #pragma unroll
            for (int pt = 0; pt < 4; ++pt) {
                float2 e = Eerd[pt * 16384 + i];
                er += e.x; ei += e.y;
            }
            #pragma unroll
            for (int pt = 0; pt < 8; ++pt) {
                float2 e = Eord[pt * 16384 + i];
                er += e.x; ei += e.y;
            }
            float2 sm = P.Sm[i];
            P.Sm[i] = make_float2(sm.x + er, sm.y + ei);
            float tot = block_reduce(er * er + ei * ei, red, tid);
            if (tid == 0) atomicAdd(P.S1, tot);
        }
        dgemm_bf<96, 384>(P.BFb, 128, 0, part * 96, P.CFr, P.CFi, QFrd, s, rg, sBu, sQ, acc);
        const int prow = rg * 8 + 2 * w, pcol = 2 * lane;
        if (part == 0) {   // subtract resolved QH[:, :128] exactly once
            if (s == 0) {
                acc[0] -= P.Cr[prow * 256 + pcol];           acc[1] -= P.Ci[prow * 256 + pcol];
                acc[2] -= P.Cr[prow * 256 + pcol + 1];       acc[3] -= P.Ci[prow * 256 + pcol + 1];
                acc[4] -= P.Cr[(prow + 1) * 256 + pcol];     acc[5] -= P.Ci[(prow + 1) * 256 + pcol];
                acc[6] -= P.Cr[(prow + 1) * 256 + pcol + 1]; acc[7] -= P.Ci[(prow + 1) * 256 + pcol + 1];
            } else {
                #pragma unroll
                for (int pt = 0; pt < 4; ++pt) {
                    const float2* qh = QHrd + pt * 32768;
                    float2 v0 = qh[prow * 256 + pcol], v1 = qh[prow * 256 + pcol + 1];
                    float2 u0 = qh[(prow + 1) * 256 + pcol], u1 = qh[(prow + 1) * 256 + pcol + 1];
                    acc[0] -= v0.x; acc[1] -= v0.y;  acc[2] -= v1.x; acc[3] -= v1.y;
                    acc[4] -= u0.x; acc[5] -= u0.y;  acc[6] -= u1.x; acc[7] -= u1.y;
                }
            }
        }
        float2* O = Eewr + part * 16384;
        *(float4*)&O[prow * 128 + pcol]       = make_float4(acc[0], acc[1], acc[2], acc[3]);
        *(float4*)&O[(prow + 1) * 128 + pcol] = make_float4(acc[4], acc[5], acc[6], acc[7]);
    } else if (b < 320) {                // ---- Eo1: QF*W1b
        int u = b - 256, rg = u >> 2, part = u & 3;
        dgemm_bf<96, 384>(P.W1b, 128, 0, part * 96, P.CFr, P.CFi, QFrd, s, rg, sBu, sQ, acc);
        float2* O = Eowr + part * 16384;
        const int prow = rg * 8 + 2 * w, pcol = 2 * lane;
        *(float4*)&O[prow * 128 + pcol]       = make_float4(acc[0], acc[1], acc[2], acc[3]);
        *(float4*)&O[(prow + 1) * 128 + pcol] = make_float4(acc[4], acc[5], acc[6], acc[7]);
    } else if (b < 384) {                // ---- Eo2: -QH*Ab[:, :128]
        int u = b - 320, rg = u >> 2, part = u & 3;
        dgemm_bf<64, 256>(P.Ab, 256, 0, part * 64, P.Cr, P.Ci, QHrd, s, rg, sBu, sQ, acc);
        float2* O = Eowr + (4 + part) * 16384;
        const int prow = rg * 8 + 2 * w, pcol = 2 * lane;
        *(float4*)&O[prow * 128 + pcol]       = make_float4(-acc[0], -acc[1], -acc[2], -acc[3]);
        *(float4*)&O[(prow + 1) * 128 + pcol] = make_float4(-acc[4], -acc[5], -acc[6], -acc[7]);
    } else {                             // ---- H: QH*AH2b
        int u = b - 384, tile = u >> 2, part = u & 3;
        int rg = tile >> 1, cs = tile & 1;
        dgemm_bf<64, 256>(P.AH2b, 256, cs << 7, part * 64, P.Cr, P.Ci, QHrd, s, rg, sBu, sQ, acc);
        float2* O = QHwr + part * 32768;
        const int prow = rg * 8 + 2 * w, pcol = (cs << 7) + 2 * lane;
        *(float4*)&O[prow * 256 + pcol]       = make_float4(acc[0], acc[1], acc[2], acc[3]);
        *(float4*)&O[(prow + 1) * 256 + pcol] = make_float4(acc[4], acc[5], acc[6], acc[7]);
    }
}

// finalize: resolve final E partials, accumulate S1/S2/SD; last of the 64
// blocks (ticket) computes the scalar output (out_kernel merged away).
__global__ __launch_bounds__(256)
void finalize_kernel(Params P) {
    __shared__ float red2[256];
    const int b = blockIdx.x, tid = threadIdx.x;
    const float2* Ee = ((KSTEPS - 1) & 1) ? P.Eep0 : P.Eep1;
    const float2* Eo = ((KSTEPS - 1) & 1) ? P.Eop0 : P.Eop1;
    int i = (b << 8) + tid;
    float er = 0.f, ei = 0.f;
    #pragma unroll
    for (int pt = 0; pt < 4; ++pt) { float2 e = Ee[pt * 16384 + i]; er += e.x; ei += e.y; }
    #pragma unroll
    for (int pt = 0; pt < 8; ++pt) { float2 e = Eo[pt * 16384 + i]; er += e.x; ei += e.y; }
    float2 sm = P.Sm[i];
    float smr = sm.x + er, smi = sm.y + ei;
    float dr = P.DFr[i], di = P.DFi[i];
    float t1 = block_reduce(er * er + ei * ei, red2, tid);
    if (tid == 0) atomicAdd(P.S1, t1);
    float t2 = block_reduce(smr * smr + smi * smi, red2, tid);
    if (tid == 0) atomicAdd(P.S2, t2);
    float t3 = block_reduce(dr * dr + di * di, red2, tid);
    if (tid == 0) atomicAdd(P.SD, t3);
    if (tid == 0) {
        __threadfence();
        unsigned int t = atomicAdd(P.tick, 1u);
        if (t == 63u) {
            __threadfence();
            float s1 = atomicAdd(P.S1, 0.f);
            float s2 = atomicAdd(P.S2, 0.f);
            float sd = atomicAdd(P.SD, 0.f);
            P.out[0] = (99.0f * (s1 + sd) + s2) / 100.0f;
        }
    }
}

extern "C" void kernel_launch(void* const* d_in, const int* in_sizes, int n_in,
                              void* d_out, int out_size, void* d_ws, size_t ws_size,
                              hipStream_t stream) {
    (void)in_sizes; (void)n_in; (void)out_size; (void)ws_size;
    char* ws = (char*)d_ws;
    Params h;
    h.Cr  = (const float*)d_in[0];
    h.Ci  = (const float*)d_in[1];
    h.Ar  = (const float*)d_in[2];
    h.Ai  = (const float*)d_in[3];
    h.AFr = (const float*)d_in[4];
    h.AFi = (const float*)d_in[5];
    h.BFr = (const float*)d_in[6];
    h.BFi = (const float*)d_in[7];
    h.CFr = (const float*)d_in[8];
    h.CFi = (const float*)d_in[9];
    h.DFr = (const float*)d_in[10];
    h.DFi = (const float*)d_in[11];
    h.A2p  = (float2*)(ws + 0);                 // 4*147456*8 = 4718592
    h.W1p  = (float2*)(ws + 4718592);           // 4*49152*8  = 1572864
    h.AH2p = (float2*)(ws + 6291456);           // 4*65536*8  = 2097152
    h.A2b  = (unsigned int*)(ws + 8388608);     // 147456*4 = 589824
    h.W1b  = (unsigned int*)(ws + 8978432);     // 196608
    h.AH2b = (unsigned int*)(ws + 9175040);     // 262144
    h.BFb  = (unsigned int*)(ws + 9437184);     // 196608
    h.Ab   = (unsigned int*)(ws + 9633792);     // 262144
    h.QFp0 = (float2*)(ws + 9895936);           // 4*49152*8 = 1572864
    h.QFp1 = (float2*)(ws + 11468800);
    h.QHp0 = (float2*)(ws + 13041664);          // 4*32768*8 = 1048576
    h.QHp1 = (float2*)(ws + 14090240);
    h.Eep0 = (float2*)(ws + 15138816);          // 4*16384*8 = 524288
    h.Eep1 = (float2*)(ws + 15663104);
    h.Eop0 = (float2*)(ws + 16187392);          // 8*16384*8 = 1048576
    h.Eop1 = (float2*)(ws + 17235968);
    h.Sm   = (float2*)(ws + 18284544);          // 131072
    h.S1   = (float*)(ws + 18415616);
    h.S2   = (float*)(ws + 18415620);
    h.SD   = (float*)(ws + 18415624);
    h.tick = (unsigned int*)(ws + 18415628);
    h.out  = (float*)d_out;

    pre1_kernel<<<1024, 256, 0, stream>>>(h);
    pre2_kernel<<<1472, 256, 0, stream>>>(h);
    for (int s = 0; s < KSTEPS - 1; ++s)
        dstep_kernel<<<512, 256, 0, stream>>>(h, s, 0);
    // last double-step: E sections only (QF/QH advance would be dead work)
    dstep_kernel<<<192, 256, 0, stream>>>(h, KSTEPS - 1, 192);
    finalize_kernel<<<64, 256, 0, stream>>>(h);
}